// Round 2
// baseline (3898.812 us; speedup 1.0000x reference)
//
#include <hip/hip_runtime.h>
#include <stdint.h>

#define S_DET 725
#define S_ANG 360
#define OUTD  512
#define NB    4

typedef float    float4v __attribute__((ext_vector_type(4)));
typedef int      int4v   __attribute__((ext_vector_type(4)));
typedef _Float16 half8   __attribute__((ext_vector_type(8)));
typedef _Float16 half4   __attribute__((ext_vector_type(4)));
typedef _Float16 half2v  __attribute__((ext_vector_type(2)));

#define GAS __attribute__((address_space(1)))
#define LAS __attribute__((address_space(3)))

// async global->LDS, 16B per lane, LDS dst wave-uniform (lane i writes dst+16*i).
// gfx9 apertures are 2^32-aligned, so low 32 bits of a flat LDS address are the
// LDS offset; inttoptr to AS(3) is the compile-safe cast.
__device__ __forceinline__ void async16(const void* src, void* lds) {
  __builtin_amdgcn_global_load_lds((const GAS void*)(uintptr_t)src,
                                   (LAS void*)(uint32_t)(uintptr_t)lds, 16, 0, 0);
}

// ---------------------------------------------------------------------------
// Weight prep: fold BN (scale into weights, offset into bias), cast to f16,
// transpose to [layer][tap][n][k] with 16B-chunk XOR swizzle: chunk g of row n
// stored at slot g^(n&7).
// ---------------------------------------------------------------------------
__global__ __launch_bounds__(256)
void prep_weights(const float* __restrict__ wsin, const float* __restrict__ sg,
                  const float* __restrict__ sb,  const float* __restrict__ sm,
                  const float* __restrict__ sv,
                  const float* __restrict__ wct, const float* __restrict__ cg,
                  const float* __restrict__ cbt, const float* __restrict__ cm,
                  const float* __restrict__ cv,
                  _Float16* __restrict__ wout, float* __restrict__ bout)
{
  int id = blockIdx.x * 256 + threadIdx.x;
  if (id >= 9 * 102400) return;
  int l   = id / 102400;          // layer 0..8 (0-3 sinogram, 4-8 image)
  int rem = id - l * 102400;      // t*4096 + k*64 + n  (source order [5][5][64][64])
  int t = rem >> 12;
  int kn = rem & 4095;
  int k = kn >> 6, n = kn & 63;
  const float *w, *g, *b, *m, *v;
  if (l < 4) { w = wsin + l*102400; g = sg + l*64; b = sb + l*64; m = sm + l*64; v = sv + l*64; }
  else { int li = l - 4; w = wct + li*102400; g = cg + li*64; b = cbt + li*64; m = cm + li*64; v = cv + li*64; }
  float s = g[n] * rsqrtf(v[n] + 1e-3f);
  float val = w[rem] * s;
  int slot = (k >> 3) ^ (n & 7);
  wout[(size_t)l*102400 + t*4096 + n*64 + slot*8 + (k & 7)] = (_Float16)val;
  if (rem < 64)  // t==0,k==0 -> n==rem
    bout[l*64 + rem] = b[rem] - m[rem] * s;
}

// ---------------------------------------------------------------------------
// First conv 1->64, bias+relu, fp32 compute, f16 output (natural [bz][y][x][c]).
// IMG=0: src inputs [B,725,360]; IMG=1: src rf table, in = 4*rf[p*4+gb].
// gb = b0 + blockIdx.z (global batch); act dst indexed by local blockIdx.z.
// ---------------------------------------------------------------------------
template <int IMG>
__global__ __launch_bounds__(256)
void conv1_kernel(const float* __restrict__ src, _Float16* __restrict__ dst,
                  const float* __restrict__ w1, const float* __restrict__ b1,
                  int H, int W, int b0)
{
  __shared__ __align__(16) float in_s[400];
  __shared__ __align__(16) float w_s[1600];
  __shared__ float b_s[64];
  const int tid = threadIdx.x;
  const int bz = blockIdx.z, gb = b0 + bz;
  const int y0 = blockIdx.y * 16, x0 = blockIdx.x * 16;
  for (int i = tid; i < 1600; i += 256) w_s[i] = w1[i];
  if (tid < 64) b_s[tid] = b1[tid];
  for (int i = tid; i < 400; i += 256) {
    int iy = i / 20, ix = i - iy * 20;
    int y = y0 - 2 + iy, x = x0 - 2 + ix;
    float v = 0.f;
    if (y >= 0 && y < H && x >= 0 && x < W) {
      if (IMG) v = 4.f * src[(size_t)(y * W + x) * 4 + gb];
      else     v = src[((size_t)gb * H + y) * W + x];
    }
    in_s[i] = v;
  }
  __syncthreads();
  const int ty = tid >> 4, tx = tid & 15;
  float acc[64];
#pragma unroll
  for (int c = 0; c < 64; ++c) acc[c] = 0.f;
  int dy = 0, dx = 0;
  for (int t = 0; t < 25; ++t) {
    float v = in_s[(ty + dy) * 20 + tx + dx];
    const float4v* wp = (const float4v*)(w_s + t * 64);
#pragma unroll
    for (int c = 0; c < 16; ++c) {
      float4v w4 = wp[c];
      acc[4*c+0] += v * w4[0]; acc[4*c+1] += v * w4[1];
      acc[4*c+2] += v * w4[2]; acc[4*c+3] += v * w4[3];
    }
    if (++dx == 5) { dx = 0; ++dy; }
  }
  const int y = y0 + ty, x = x0 + tx;
  if (y < H && x < W) {
    uint32_t* dp = (uint32_t*)(dst + ((size_t)(bz * H + y) * W + x) * 64);
#pragma unroll
    for (int c = 0; c < 32; ++c) {
      float v0 = acc[2*c]   + b_s[2*c];   v0 = v0 > 0.f ? v0 : 0.f;
      float v1 = acc[2*c+1] + b_s[2*c+1]; v1 = v1 > 0.f ? v1 : 0.f;
      half2v h = { (_Float16)v0, (_Float16)v1 };
      dp[c] = __builtin_bit_cast(uint32_t, h);
    }
  }
}

// ---------------------------------------------------------------------------
// Residual-block conv 64->64 + folded-BN bias + relu via MFMA 16x16x32 f16.
// Output tile 12 rows x 16 cols; input tile 16x20 px x 64ch in LDS (XOR-chunk
// swizzled, 128B/pixel). Weights = A operand (M=64 out-ch), pixels = B operand.
// Per tap: double-buffered 8KB weight stage + 2 K-chunks of 12 MFMAs per wave.
// ---------------------------------------------------------------------------
__global__ __launch_bounds__(256, 2)
void mid_conv(const _Float16* __restrict__ src, _Float16* __restrict__ dst,
              const _Float16* __restrict__ wt, const float* __restrict__ bias,
              const char* __restrict__ zbuf, int H, int W)
{
  __shared__ __align__(16) char smem[40960 + 2 * 8192];  // A-tile + 2 weight bufs
  char* const atile = smem;
  const int tid = threadIdx.x;
  const int wv = tid >> 6, ln = tid & 63;
  const int b = blockIdx.z;
  const int y0 = blockIdx.y * 12, x0 = blockIdx.x * 16;

  // stage input tile: 320 px * 8 chunks = 40 wave-instructions
#pragma unroll
  for (int j = 0; j < 10; ++j) {
    const int inst = wv * 10 + j;
    const int slot = inst * 64 + ln;
    const int p = slot >> 3, gp = slot & 7;
    const int g = gp ^ (p & 7);
    const int iy = p / 20, ix = p - iy * 20;
    const int y = y0 - 2 + iy, x = x0 - 2 + ix;
    const char* sp = (y >= 0 && y < H && x >= 0 && x < W)
        ? (const char*)(src + ((size_t)(b * H + y) * W + x) * 64) + g * 16
        : zbuf + g * 16;
    async16(sp, atile + inst * 1024);
  }
  // stage tap-0 weights into buffer 0
#pragma unroll
  for (int j = 0; j < 2; ++j) {
    const int inst = wv * 2 + j;
    async16((const char*)wt + inst * 1024 + ln * 16, smem + 40960 + inst * 1024);
  }
  __syncthreads();

  float4v acc[3][4];
#pragma unroll
  for (int pi = 0; pi < 3; ++pi)
#pragma unroll
    for (int ci = 0; ci < 4; ++ci) acc[pi][ci] = (float4v){0.f, 0.f, 0.f, 0.f};

  int dy = 0, dx = 0;
  for (int t = 0; t < 25; ++t) {
    if (t < 24) {  // prefetch next tap's weights into the other buffer
      char* wdst = smem + 40960 + ((t + 1) & 1) * 8192;
#pragma unroll
      for (int j = 0; j < 2; ++j) {
        const int inst = wv * 2 + j;
        async16((const char*)wt + (t + 1) * 8192 + inst * 1024 + ln * 16,
                wdst + inst * 1024);
      }
    }
    const char* wb = smem + 40960 + (t & 1) * 8192;
#pragma unroll
    for (int kc = 0; kc < 2; ++kc) {
      const int g0 = kc * 4 + (ln >> 4);
      half8 wf[4], af[3];
#pragma unroll
      for (int ci = 0; ci < 4; ++ci) {
        const int ch = ci * 16 + (ln & 15);
        wf[ci] = *(const half8*)(wb + ch * 128 + ((g0 ^ (ch & 7)) << 4));
      }
#pragma unroll
      for (int pi = 0; pi < 3; ++pi) {
        const int p = (wv * 3 + pi + dy) * 20 + (ln & 15) + dx;
        af[pi] = *(const half8*)(atile + p * 128 + ((g0 ^ (p & 7)) << 4));
      }
#pragma unroll
      for (int pi = 0; pi < 3; ++pi)
#pragma unroll
        for (int ci = 0; ci < 4; ++ci)
          acc[pi][ci] = __builtin_amdgcn_mfma_f32_16x16x32_f16(
              wf[ci], af[pi], acc[pi][ci], 0, 0, 0);
    }
    if (++dx == 5) { dx = 0; ++dy; }
    __syncthreads();
  }

  // epilogue: D[m=ch][n=pixel]; lane holds 4 consecutive channels of 1 pixel
  const int tx = ln & 15;
  const int x = x0 + tx;
#pragma unroll
  for (int pi = 0; pi < 3; ++pi) {
    const int y = y0 + wv * 3 + pi;
    if (y < H && x < W) {
      _Float16* dp = dst + ((size_t)(b * H + y) * W + x) * 64;
#pragma unroll
      for (int ci = 0; ci < 4; ++ci) {
        const int cbase = ci * 16 + (ln >> 4) * 4;
        const float4v bv = *(const float4v*)(bias + cbase);
        half4 h;
#pragma unroll
        for (int r = 0; r < 4; ++r) {
          float v = acc[pi][ci][r] + bv[r];
          v = v > 0.f ? v : 0.f;
          h[r] = (_Float16)v;
        }
        *(half4*)(dp + cbase) = h;
      }
    }
  }
}

// ---------------------------------------------------------------------------
// 64->1 conv of one activation map, accumulated (+=) into fp32 buffer.
// conv(pp, w6) = sum_i conv(de_i, w6)  => no pp buffer needed, fp32 accurate.
// ---------------------------------------------------------------------------
__global__ __launch_bounds__(256, 2)
void fc_accum(const _Float16* __restrict__ src, float* __restrict__ accum,
              const float* __restrict__ w6, const char* __restrict__ zbuf,
              int H, int W, int b0)
{
  __shared__ __align__(16) char smem[51200 + 3200];  // 400px tile + w6 as f16
  char* const atile = smem;
  _Float16* const wl = (_Float16*)(smem + 51200);
  const int tid = threadIdx.x;
  const int wv = tid >> 6, ln = tid & 63;
  const int bz = blockIdx.z, gb = b0 + bz;
  const int y0 = blockIdx.y * 16, x0 = blockIdx.x * 16;
  for (int i = tid; i < 1600; i += 256) wl[i] = (_Float16)w6[i];
  for (int inst = wv; inst < 50; inst += 4) {
    const int slot = inst * 64 + ln;
    const int p = slot >> 3, gp = slot & 7;
    const int g = gp ^ (p & 7);
    const int iy = p / 20, ix = p - iy * 20;
    const int y = y0 - 2 + iy, x = x0 - 2 + ix;
    const char* sp = (y >= 0 && y < H && x >= 0 && x < W)
        ? (const char*)(src + ((size_t)(bz * H + y) * W + x) * 64) + g * 16
        : zbuf + g * 16;
    async16(sp, atile + inst * 1024);
  }
  __syncthreads();
  const int ty = tid >> 4, tx = tid & 15;
  float sum = 0.f;
  int dy = 0, dxx = 0;
  for (int t = 0; t < 25; ++t) {
    const int p = (ty + dy) * 20 + tx + dxx;
    const char* pb = atile + p * 128;
    const int pk = p & 7;
    const half2v* wp = (const half2v*)(wl + t * 64);
#pragma unroll
    for (int g = 0; g < 8; ++g) {
      half8 h = *(const half8*)(pb + ((g ^ pk) << 4));
#pragma unroll
      for (int q = 0; q < 4; ++q) {
        half2v a = { h[2*q], h[2*q+1] };
        sum = __builtin_amdgcn_fdot2(a, wp[g * 4 + q], sum, false);
      }
    }
    if (++dxx == 5) { dxx = 0; ++dy; }
  }
  const int y = y0 + ty, x = x0 + tx;
  if (y < H && x < W) accum[((size_t)gb * H + y) * W + x] += sum;
}

// ---------------------------------------------------------------------------
// de_sin = acc/4 + b_sin6 + inputs    (written to d_out slot 0)
// ---------------------------------------------------------------------------
__global__ __launch_bounds__(256)
void write_desin(const float* __restrict__ accf, const float* __restrict__ inputs,
                 const float* __restrict__ b6, float* __restrict__ out)
{
  int id = blockIdx.x * 256 + threadIdx.x;
  if (id < NB * S_DET * S_ANG) out[id] = accf[id] * 0.25f + b6[0] + inputs[id];
}

// ---------------------------------------------------------------------------
// Ramp filter: 725-tap SAME 1D conv along detector axis. One block per
// (batch, angle); 6 consecutive outputs/thread, sliding register window.
// Output f2v[(a*725+s)*4 + b] (float4 rows for the backprojection gather).
// ---------------------------------------------------------------------------
__global__ __launch_bounds__(128)
void ramp_filter(const float* __restrict__ desin, const float* __restrict__ wb,
                 float* __restrict__ f2v)
{
  __shared__ float col[1472];   // zero-padded: data at [368, 368+725)
  __shared__ float wl[725];
  const int blk = blockIdx.x;
  const int b = blk / 360, a = blk - b * 360;
  const int tid = threadIdx.x;
  for (int i = tid; i < 1472; i += 128) col[i] = 0.f;
  for (int i = tid; i < 725; i += 128) wl[i] = wb[i];
  __syncthreads();
  for (int i = tid; i < 725; i += 128) col[368 + i] = desin[(b * 725 + i) * 360 + a];
  __syncthreads();
  const int s0 = tid * 6;
  if (s0 < 725) {
    float o0 = 0, o1 = 0, o2 = 0, o3 = 0, o4 = 0, o5 = 0;
    const float* cb = col + 6 + s0;  // cb[t+j] = x[s0+j + t - 362]
    float r0 = cb[0], r1 = cb[1], r2 = cb[2], r3 = cb[3], r4 = cb[4], r5 = cb[5];
    for (int t = 0; t < 725; ++t) {
      float w = wl[t];
      o0 += r0 * w; o1 += r1 * w; o2 += r2 * w;
      o3 += r3 * w; o4 += r4 * w; o5 += r5 * w;
      r0 = r1; r1 = r2; r2 = r3; r3 = r4; r4 = r5; r5 = cb[t + 6];
    }
    float o[6] = { o0, o1, o2, o3, o4, o5 };
#pragma unroll
    for (int j = 0; j < 6; ++j)
      if (s0 + j < 725) f2v[((size_t)a * 725 + s0 + j) * 4 + b] = o[j];
  }
}

// ---------------------------------------------------------------------------
// Sparse backprojection: rows sorted -> run-length accumulate 16 nnz/thread,
// flush with 4 atomicAdds on row change into rf[row][4].
// ---------------------------------------------------------------------------
__global__ __launch_bounds__(256)
void backproj(const float* __restrict__ vals, const int* __restrict__ rows,
              const int* __restrict__ cols, const float* __restrict__ f2v,
              float* __restrict__ rf)
{
  const int tid = blockIdx.x * 256 + threadIdx.x;   // 524288 threads
  const int i0 = tid * 16;
  const int4v* rp = (const int4v*)(rows + i0);
  const int4v* cp = (const int4v*)(cols + i0);
  const float4v* vp = (const float4v*)(vals + i0);
  float a0 = 0, a1 = 0, a2 = 0, a3 = 0;
  int cur = rows[i0];
#pragma unroll
  for (int q = 0; q < 4; ++q) {
    int4v r4 = rp[q]; int4v c4 = cp[q]; float4v v4 = vp[q];
#pragma unroll
    for (int u = 0; u < 4; ++u) {
      int r = r4[u]; int c = c4[u]; float v = v4[u];
      if (r != cur) {
        atomicAdd(rf + (size_t)cur * 4 + 0, a0);
        atomicAdd(rf + (size_t)cur * 4 + 1, a1);
        atomicAdd(rf + (size_t)cur * 4 + 2, a2);
        atomicAdd(rf + (size_t)cur * 4 + 3, a3);
        a0 = a1 = a2 = a3 = 0; cur = r;
      }
      const float4v f = *(const float4v*)(f2v + (size_t)c * 4);
      a0 += v * f[0]; a1 += v * f[1]; a2 += v * f[2]; a3 += v * f[3];
    }
  }
  atomicAdd(rf + (size_t)cur * 4 + 0, a0);
  atomicAdd(rf + (size_t)cur * 4 + 1, a1);
  atomicAdd(rf + (size_t)cur * 4 + 2, a2);
  atomicAdd(rf + (size_t)cur * 4 + 3, a3);
}

__global__ __launch_bounds__(256)
void write_fbp(const float* __restrict__ rf, float* __restrict__ out)
{
  int id = blockIdx.x * 256 + threadIdx.x;  // 4*262144 exact
  int b = id >> 18, p = id & 262143;
  out[id] = 4.f * rf[(size_t)p * 4 + b];
}

__global__ __launch_bounds__(256)
void write_outputs(const float* __restrict__ accf, const float* __restrict__ rf,
                   const float* __restrict__ b6, float* __restrict__ out)
{
  int id = blockIdx.x * 256 + threadIdx.x;  // 4*262144 exact
  int b = id >> 18, p = id & 262143;
  out[id] = accf[id] * 0.2f + b6[0] + 4.f * rf[(size_t)p * 4 + b];
}

// ---------------------------------------------------------------------------
extern "C" void kernel_launch(void* const* d_in, const int* in_sizes, int n_in,
                              void* d_out, int out_size, void* d_ws, size_t ws_size,
                              hipStream_t stream)
{
  (void)in_sizes; (void)n_in; (void)out_size;
  const float* inputs   = (const float*)d_in[0];
  const float* w_sin1   = (const float*)d_in[1];
  const float* b_sin1   = (const float*)d_in[2];
  const float* w_sin_mid= (const float*)d_in[3];
  const float* sin_gamma= (const float*)d_in[4];
  const float* sin_beta = (const float*)d_in[5];
  const float* sin_mean = (const float*)d_in[6];
  const float* sin_var  = (const float*)d_in[7];
  const float* w_sin6   = (const float*)d_in[8];
  const float* b_sin6   = (const float*)d_in[9];
  const float* w_ct1    = (const float*)d_in[10];
  const float* b_ct1    = (const float*)d_in[11];
  const float* w_ct_mid = (const float*)d_in[12];
  const float* ct_gamma = (const float*)d_in[13];
  const float* ct_beta  = (const float*)d_in[14];
  const float* ct_mean  = (const float*)d_in[15];
  const float* ct_var   = (const float*)d_in[16];
  const float* w_ct6    = (const float*)d_in[17];
  const float* b_ct6    = (const float*)d_in[18];
  const float* w_b      = (const float*)d_in[19];
  const float* at_vals  = (const float*)d_in[20];
  const int*   at_rows  = (const int*)d_in[21];
  const int*   at_cols  = (const int*)d_in[22];
  float* out = (float*)d_out;

  // ---- workspace budget: full 4-batch mode needs ~279 MB; per-batch ~78 MB.
  const bool full = ws_size >= (size_t)300 * 1024 * 1024;
  const int nbat  = full ? 4 : 1;
  const int npass = full ? 1 : 4;

  char* ws = (char*)d_ws;
  size_t off = 0;
  auto alloc = [&](size_t bytes) {
    char* p = ws + off;
    off = (off + bytes + 255) & ~(size_t)255;
    return p;
  };
  char*     zbuf    = alloc(256);
  _Float16* wmid    = (_Float16*)alloc((size_t)9 * 102400 * 2);
  float*    biasmid = (float*)alloc(9 * 64 * 4);
  float*    rf      = (float*)alloc((size_t)262144 * 16);
  char*     shreg   = alloc((size_t)262144 * 16);  // f2v (4.18MB) / acc_fc (4.19MB) union
  _Float16* act_a   = (_Float16*)alloc((size_t)nbat * 262144 * 128);
  _Float16* act_b   = (_Float16*)alloc((size_t)nbat * 262144 * 128);
  float* f2v    = (float*)shreg;
  float* acc_fc = (float*)shreg;

  hipMemsetAsync(zbuf, 0, 256, stream);
  hipMemsetAsync(rf, 0, (size_t)262144 * 16, stream);
  hipMemsetAsync(acc_fc, 0, (size_t)262144 * 16, stream);

  prep_weights<<<3600, 256, 0, stream>>>(w_sin_mid, sin_gamma, sin_beta, sin_mean, sin_var,
                                         w_ct_mid, ct_gamma, ct_beta, ct_mean, ct_var,
                                         wmid, biasmid);

  // ---- sinogram CNN (H=725, W=360) ----
  for (int p = 0; p < npass; ++p) {
    const int b0 = p * nbat;
    conv1_kernel<0><<<dim3(23, 46, nbat), 256, 0, stream>>>(inputs, act_a, w_sin1, b_sin1,
                                                            725, 360, b0);
    fc_accum<<<dim3(23, 46, nbat), 256, 0, stream>>>(act_a, acc_fc, w_sin6, zbuf, 725, 360, b0);
    _Float16* cur = act_a; _Float16* nxt = act_b;
    for (int i = 0; i < 4; ++i) {
      mid_conv<<<dim3(23, 61, nbat), 256, 0, stream>>>(cur, nxt, wmid + (size_t)i * 102400,
                                                       biasmid + i * 64, zbuf, 725, 360);
      fc_accum<<<dim3(23, 46, nbat), 256, 0, stream>>>(nxt, acc_fc, w_sin6, zbuf, 725, 360, b0);
      _Float16* t = cur; cur = nxt; nxt = t;
    }
  }
  write_desin<<<4079, 256, 0, stream>>>(acc_fc, inputs, b_sin6, out);

  // ---- FBP ----
  ramp_filter<<<1440, 128, 0, stream>>>(out, w_b, f2v);
  backproj<<<2048, 256, 0, stream>>>(at_vals, at_rows, at_cols, f2v, rf);
  write_fbp<<<4096, 256, 0, stream>>>(rf, out + 2092576);

  // ---- image CNN (H=W=512) ----
  hipMemsetAsync(acc_fc, 0, (size_t)262144 * 16, stream);
  for (int p = 0; p < npass; ++p) {
    const int b0 = p * nbat;
    conv1_kernel<1><<<dim3(32, 32, nbat), 256, 0, stream>>>(rf, act_a, w_ct1, b_ct1,
                                                            512, 512, b0);
    fc_accum<<<dim3(32, 32, nbat), 256, 0, stream>>>(act_a, acc_fc, w_ct6, zbuf, 512, 512, b0);
    _Float16* cur = act_a; _Float16* nxt = act_b;
    for (int i = 0; i < 5; ++i) {
      mid_conv<<<dim3(32, 43, nbat), 256, 0, stream>>>(cur, nxt, wmid + (size_t)(4 + i) * 102400,
                                                       biasmid + (4 + i) * 64, zbuf, 512, 512);
      fc_accum<<<dim3(32, 32, nbat), 256, 0, stream>>>(nxt, acc_fc, w_ct6, zbuf, 512, 512, b0);
      _Float16* t = cur; cur = nxt; nxt = t;
    }
  }
  write_outputs<<<4096, 256, 0, stream>>>(acc_fc, rf, b_ct6, out + 1044000);
}

// Round 3
// 3074.280 us; speedup vs baseline: 1.2682x; 1.2682x over previous
//
#include <hip/hip_runtime.h>
#include <stdint.h>

#define S_DET 725
#define S_ANG 360
#define OUTD  512
#define NB    4

typedef float    float4v __attribute__((ext_vector_type(4)));
typedef int      int4v   __attribute__((ext_vector_type(4)));
typedef _Float16 half8   __attribute__((ext_vector_type(8)));
typedef _Float16 half4   __attribute__((ext_vector_type(4)));
typedef _Float16 half2v  __attribute__((ext_vector_type(2)));

#define GAS __attribute__((address_space(1)))
#define LAS __attribute__((address_space(3)))

// async global->LDS, 16B per lane, LDS dst wave-uniform (lane i writes dst+16*i)
__device__ __forceinline__ void async16(const void* src, void* lds) {
  __builtin_amdgcn_global_load_lds((const GAS void*)(uintptr_t)src,
                                   (LAS void*)(uint32_t)(uintptr_t)lds, 16, 0, 0);
}

// ---------------------------------------------------------------------------
// Weight prep: fold BN into weights/bias, cast f16, transpose to [tap][n][k]
// with 16B-chunk XOR swizzle (chunk g of row n at slot g^(n&7)). Tail ids
// pack w_sin6/w_ct6 to f16 [tap][k] for the fused-fc MFMA row.
// ---------------------------------------------------------------------------
__global__ __launch_bounds__(256)
void prep_weights(const float* __restrict__ wsin, const float* __restrict__ sg,
                  const float* __restrict__ sb,  const float* __restrict__ sm,
                  const float* __restrict__ sv,
                  const float* __restrict__ wct, const float* __restrict__ cg,
                  const float* __restrict__ cbt, const float* __restrict__ cm,
                  const float* __restrict__ cv,
                  const float* __restrict__ wsin6, const float* __restrict__ wct6,
                  _Float16* __restrict__ wout, float* __restrict__ bout,
                  _Float16* __restrict__ w6out)
{
  int id = blockIdx.x * 256 + threadIdx.x;
  if (id < 9 * 102400) {
    int l   = id / 102400;          // layer 0..8 (0-3 sinogram, 4-8 image)
    int rem = id - l * 102400;      // t*4096 + k*64 + n  (source [5][5][64][64])
    int t = rem >> 12;
    int kn = rem & 4095;
    int k = kn >> 6, n = kn & 63;
    const float *w, *g, *b, *m, *v;
    if (l < 4) { w = wsin + l*102400; g = sg + l*64; b = sb + l*64; m = sm + l*64; v = sv + l*64; }
    else { int li = l - 4; w = wct + li*102400; g = cg + li*64; b = cbt + li*64; m = cm + li*64; v = cv + li*64; }
    float s = g[n] * rsqrtf(v[n] + 1e-3f);
    float val = w[rem] * s;
    int slot = (k >> 3) ^ (n & 7);
    wout[(size_t)l*102400 + t*4096 + n*64 + slot*8 + (k & 7)] = (_Float16)val;
    if (rem < 64)  // t==0,k==0 -> n==rem
      bout[l*64 + rem] = b[rem] - m[rem] * s;
  } else {
    int r = id - 9 * 102400;
    if (r < 3200)  // [0,1600) sino w6, [1600,3200) ct w6; layout [t*64+k]
      w6out[r] = (_Float16)(r < 1600 ? wsin6[r] : wct6[r - 1600]);
  }
}

// ---------------------------------------------------------------------------
// First conv 1->64, bias+relu, fp32 compute, f16 output [bz][y][x][c].
// IMG=0: src inputs [B,725,360]; IMG=1: src rf table, in = 4*rf[p*4+gb].
// ---------------------------------------------------------------------------
template <int IMG>
__global__ __launch_bounds__(256)
void conv1_kernel(const float* __restrict__ src, _Float16* __restrict__ dst,
                  const float* __restrict__ w1, const float* __restrict__ b1,
                  int H, int W, int b0)
{
  __shared__ __align__(16) float in_s[400];
  __shared__ __align__(16) float w_s[1600];
  __shared__ float b_s[64];
  const int tid = threadIdx.x;
  const int bz = blockIdx.z, gb = b0 + bz;
  const int y0 = blockIdx.y * 16, x0 = blockIdx.x * 16;
  for (int i = tid; i < 1600; i += 256) w_s[i] = w1[i];
  if (tid < 64) b_s[tid] = b1[tid];
  for (int i = tid; i < 400; i += 256) {
    int iy = i / 20, ix = i - iy * 20;
    int y = y0 - 2 + iy, x = x0 - 2 + ix;
    float v = 0.f;
    if (y >= 0 && y < H && x >= 0 && x < W) {
      if (IMG) v = 4.f * src[(size_t)(y * W + x) * 4 + gb];
      else     v = src[((size_t)gb * H + y) * W + x];
    }
    in_s[i] = v;
  }
  __syncthreads();
  const int ty = tid >> 4, tx = tid & 15;
  float acc[64];
#pragma unroll
  for (int c = 0; c < 64; ++c) acc[c] = 0.f;
  int dy = 0, dx = 0;
  for (int t = 0; t < 25; ++t) {
    float v = in_s[(ty + dy) * 20 + tx + dx];
    const float4v* wp = (const float4v*)(w_s + t * 64);
#pragma unroll
    for (int c = 0; c < 16; ++c) {
      float4v w4 = wp[c];
      acc[4*c+0] += v * w4[0]; acc[4*c+1] += v * w4[1];
      acc[4*c+2] += v * w4[2]; acc[4*c+3] += v * w4[3];
    }
    if (++dx == 5) { dx = 0; ++dy; }
  }
  const int y = y0 + ty, x = x0 + tx;
  if (y < H && x < W) {
    uint32_t* dp = (uint32_t*)(dst + ((size_t)(bz * H + y) * W + x) * 64);
#pragma unroll
    for (int c = 0; c < 32; ++c) {
      float v0 = acc[2*c]   + b_s[2*c];   v0 = v0 > 0.f ? v0 : 0.f;
      float v1 = acc[2*c+1] + b_s[2*c+1]; v1 = v1 > 0.f ? v1 : 0.f;
      half2v h = { (_Float16)v0, (_Float16)v1 };
      dp[c] = __builtin_bit_cast(uint32_t, h);
    }
  }
}

// ---------------------------------------------------------------------------
// Residual conv 64->64 + folded-BN bias + relu via MFMA 16x16x32 f16, PLUS
// fused fc: w6 rides as an extra A-operand whose m=0 row is w6[tap][k]
// (other rows read a zero slot), consuming the same B pixel frags -> fc of
// the INPUT map lands in acc6 for free; += into accum (block interiors are
// disjoint). Output tile 16x16; input tile 20x20 px x 64ch in LDS.
// ---------------------------------------------------------------------------
__global__ __launch_bounds__(256, 2)
void mid_conv(const _Float16* __restrict__ src, _Float16* __restrict__ dst,
              float* __restrict__ accum,
              const _Float16* __restrict__ wt, const _Float16* __restrict__ w6g,
              const float* __restrict__ bias, const char* __restrict__ zbuf,
              int H, int W, int b0)
{
  __shared__ __align__(16) char smem[51200 + 2 * 8192 + 3200 + 16];
  char* const atile = smem;                       // 400 px * 128B
  char* const wbuf  = smem + 51200;               // 2 x 8KB weight dbuf
  _Float16* const w6l = (_Float16*)(smem + 51200 + 16384);  // 25x64 f16
  char* const zl = smem + 51200 + 16384 + 3200;   // 16B zeros
  const int tid = threadIdx.x;
  const int wv = tid >> 6, ln = tid & 63;
  const int bz = blockIdx.z, gb = b0 + bz;
  const int y0 = blockIdx.y * 16, x0 = blockIdx.x * 16;

  if (tid < 200) ((half8*)w6l)[tid] = ((const half8*)w6g)[tid];
  if (tid < 4) ((int*)zl)[tid] = 0;

  // stage input tile: 400 px * 8 chunks = 50 wave-instructions
  for (int inst = wv; inst < 50; inst += 4) {
    const int slot = inst * 64 + ln;
    const int p = slot >> 3, gp = slot & 7;
    const int g = gp ^ (p & 7);
    const int iy = p / 20, ix = p - iy * 20;
    const int y = y0 - 2 + iy, x = x0 - 2 + ix;
    const char* sp = (y >= 0 && y < H && x >= 0 && x < W)
        ? (const char*)(src + ((size_t)(bz * H + y) * W + x) * 64) + g * 16
        : zbuf + g * 16;
    async16(sp, atile + inst * 1024);
  }
  // tap-0 weights into buffer 0
#pragma unroll
  for (int j = 0; j < 2; ++j) {
    const int inst = wv * 2 + j;
    async16((const char*)wt + inst * 1024 + ln * 16, wbuf + inst * 1024);
  }
  __syncthreads();

  float4v acc[4][4];
  float4v acc6[4];
#pragma unroll
  for (int pi = 0; pi < 4; ++pi) {
    acc6[pi] = (float4v){0.f, 0.f, 0.f, 0.f};
#pragma unroll
    for (int ci = 0; ci < 4; ++ci) acc[pi][ci] = (float4v){0.f, 0.f, 0.f, 0.f};
  }

  int dy = 0, dx = 0;
  for (int t = 0; t < 25; ++t) {
    if (t < 24) {  // prefetch next tap's weights into the other buffer
      char* wdst = wbuf + ((t + 1) & 1) * 8192;
#pragma unroll
      for (int j = 0; j < 2; ++j) {
        const int inst = wv * 2 + j;
        async16((const char*)wt + (t + 1) * 8192 + inst * 1024 + ln * 16,
                wdst + inst * 1024);
      }
    }
    const char* wb = wbuf + (t & 1) * 8192;
#pragma unroll
    for (int kc = 0; kc < 2; ++kc) {
      const int g0 = kc * 4 + (ln >> 4);
      half8 wf[4], af[4], wf6;
#pragma unroll
      for (int ci = 0; ci < 4; ++ci) {
        const int ch = ci * 16 + (ln & 15);
        wf[ci] = *(const half8*)(wb + ch * 128 + ((g0 ^ (ch & 7)) << 4));
      }
      wf6 = *(const half8*)((ln & 15) == 0
                ? (const char*)(w6l + t * 64 + kc * 32 + ((ln >> 4) << 3))
                : zl);
#pragma unroll
      for (int pi = 0; pi < 4; ++pi) {
        const int p = (wv * 4 + pi + dy) * 20 + (ln & 15) + dx;
        af[pi] = *(const half8*)(atile + p * 128 + ((g0 ^ (p & 7)) << 4));
      }
#pragma unroll
      for (int pi = 0; pi < 4; ++pi) {
#pragma unroll
        for (int ci = 0; ci < 4; ++ci)
          acc[pi][ci] = __builtin_amdgcn_mfma_f32_16x16x32_f16(
              wf[ci], af[pi], acc[pi][ci], 0, 0, 0);
        acc6[pi] = __builtin_amdgcn_mfma_f32_16x16x32_f16(
            wf6, af[pi], acc6[pi], 0, 0, 0);
      }
    }
    if (++dx == 5) { dx = 0; ++dy; }
    __syncthreads();
  }

  // epilogue: D[m=ch][n=px]; lane holds 4 consecutive channels of 1 pixel
  const int tx = ln & 15;
  const int x = x0 + tx;
#pragma unroll
  for (int pi = 0; pi < 4; ++pi) {
    const int y = y0 + wv * 4 + pi;
    if (y < H && x < W) {
      _Float16* dp = dst + ((size_t)(bz * H + y) * W + x) * 64;
#pragma unroll
      for (int ci = 0; ci < 4; ++ci) {
        const int cbase = ci * 16 + (ln >> 4) * 4;
        const float4v bv = *(const float4v*)(bias + cbase);
        half4 h;
#pragma unroll
        for (int r = 0; r < 4; ++r) {
          float v = acc[pi][ci][r] + bv[r];
          v = v > 0.f ? v : 0.f;
          h[r] = (_Float16)v;
        }
        *(half4*)(dp + cbase) = h;
      }
    }
  }
  // fused fc of the input map: D row m=0 lives in lanes 0..15, reg 0
  if (ln < 16) {
#pragma unroll
    for (int pi = 0; pi < 4; ++pi) {
      const int y = y0 + wv * 4 + pi, x2 = x0 + ln;
      if (y < H && x2 < W)
        accum[((size_t)gb * H + y) * W + x2] += acc6[pi][0];
    }
  }
}

// ---------------------------------------------------------------------------
// Standalone 64->1 conv (only for the LAST activation map of each chain).
// ---------------------------------------------------------------------------
__global__ __launch_bounds__(256, 2)
void fc_accum(const _Float16* __restrict__ src, float* __restrict__ accum,
              const float* __restrict__ w6, const char* __restrict__ zbuf,
              int H, int W, int b0)
{
  __shared__ __align__(16) char smem[51200 + 3200];
  char* const atile = smem;
  _Float16* const wl = (_Float16*)(smem + 51200);
  const int tid = threadIdx.x;
  const int wv = tid >> 6, ln = tid & 63;
  const int bz = blockIdx.z, gb = b0 + bz;
  const int y0 = blockIdx.y * 16, x0 = blockIdx.x * 16;
  for (int i = tid; i < 1600; i += 256) wl[i] = (_Float16)w6[i];
  for (int inst = wv; inst < 50; inst += 4) {
    const int slot = inst * 64 + ln;
    const int p = slot >> 3, gp = slot & 7;
    const int g = gp ^ (p & 7);
    const int iy = p / 20, ix = p - iy * 20;
    const int y = y0 - 2 + iy, x = x0 - 2 + ix;
    const char* sp = (y >= 0 && y < H && x >= 0 && x < W)
        ? (const char*)(src + ((size_t)(bz * H + y) * W + x) * 64) + g * 16
        : zbuf + g * 16;
    async16(sp, atile + inst * 1024);
  }
  __syncthreads();
  const int ty = tid >> 4, tx = tid & 15;
  float sum = 0.f;
  int dy = 0, dxx = 0;
  for (int t = 0; t < 25; ++t) {
    const int p = (ty + dy) * 20 + tx + dxx;
    const char* pb = atile + p * 128;
    const int pk = p & 7;
    const half2v* wp = (const half2v*)(wl + t * 64);
#pragma unroll
    for (int g = 0; g < 8; ++g) {
      half8 h = *(const half8*)(pb + ((g ^ pk) << 4));
#pragma unroll
      for (int q = 0; q < 4; ++q) {
        half2v a = { h[2*q], h[2*q+1] };
        sum = __builtin_amdgcn_fdot2(a, wp[g * 4 + q], sum, false);
      }
    }
    if (++dxx == 5) { dxx = 0; ++dy; }
  }
  const int y = y0 + ty, x = x0 + tx;
  if (y < H && x < W) accum[((size_t)gb * H + y) * W + x] += sum;
}

// ---------------------------------------------------------------------------
__global__ __launch_bounds__(256)
void write_desin(const float* __restrict__ accf, const float* __restrict__ inputs,
                 const float* __restrict__ b6, float* __restrict__ out)
{
  int id = blockIdx.x * 256 + threadIdx.x;
  if (id < NB * S_DET * S_ANG) out[id] = accf[id] * 0.25f + b6[0] + inputs[id];
}

// ---------------------------------------------------------------------------
// Ramp filter: 725-tap SAME 1D conv along detector axis; one block per
// (batch, angle); output packed f16 rows f2h[(a*725+s)*4 + b].
// ---------------------------------------------------------------------------
__global__ __launch_bounds__(128)
void ramp_filter(const float* __restrict__ desin, const float* __restrict__ wb,
                 _Float16* __restrict__ f2h)
{
  __shared__ float col[1472];   // zero-padded: data at [368, 368+725)
  __shared__ float wl[725];
  const int blk = blockIdx.x;
  const int b = blk / 360, a = blk - b * 360;
  const int tid = threadIdx.x;
  for (int i = tid; i < 1472; i += 128) col[i] = 0.f;
  for (int i = tid; i < 725; i += 128) wl[i] = wb[i];
  __syncthreads();
  for (int i = tid; i < 725; i += 128) col[368 + i] = desin[(b * 725 + i) * 360 + a];
  __syncthreads();
  const int s0 = tid * 6;
  if (s0 < 725) {
    float o0 = 0, o1 = 0, o2 = 0, o3 = 0, o4 = 0, o5 = 0;
    const float* cb = col + 6 + s0;  // cb[t+j] = x[s0+j + t - 362]
    float r0 = cb[0], r1 = cb[1], r2 = cb[2], r3 = cb[3], r4 = cb[4], r5 = cb[5];
    for (int t = 0; t < 725; ++t) {
      float w = wl[t];
      o0 += r0 * w; o1 += r1 * w; o2 += r2 * w;
      o3 += r3 * w; o4 += r4 * w; o5 += r5 * w;
      r0 = r1; r1 = r2; r2 = r3; r3 = r4; r4 = r5; r5 = cb[t + 6];
    }
    float o[6] = { o0, o1, o2, o3, o4, o5 };
#pragma unroll
    for (int j = 0; j < 6; ++j)
      if (s0 + j < 725) f2h[((size_t)a * 725 + s0 + j) * 4 + b] = (_Float16)o[j];
  }
}

// ---------------------------------------------------------------------------
// Sparse backprojection: rows sorted -> run-length accumulate 16 nnz/thread,
// flush with 4 atomicAdds on row change. f2h gathers are 8B (fp16 x4).
// ---------------------------------------------------------------------------
__global__ __launch_bounds__(256)
void backproj(const float* __restrict__ vals, const int* __restrict__ rows,
              const int* __restrict__ cols, const _Float16* __restrict__ f2h,
              float* __restrict__ rf)
{
  const int tid = blockIdx.x * 256 + threadIdx.x;   // 524288 threads
  const int i0 = tid * 16;
  const int4v* rp = (const int4v*)(rows + i0);
  const int4v* cp = (const int4v*)(cols + i0);
  const float4v* vp = (const float4v*)(vals + i0);
  float a0 = 0, a1 = 0, a2 = 0, a3 = 0;
  int cur = rows[i0];
#pragma unroll
  for (int q = 0; q < 4; ++q) {
    int4v r4 = rp[q]; int4v c4 = cp[q]; float4v v4 = vp[q];
#pragma unroll
    for (int u = 0; u < 4; ++u) {
      int r = r4[u]; int c = c4[u]; float v = v4[u];
      if (r != cur) {
        atomicAdd(rf + (size_t)cur * 4 + 0, a0);
        atomicAdd(rf + (size_t)cur * 4 + 1, a1);
        atomicAdd(rf + (size_t)cur * 4 + 2, a2);
        atomicAdd(rf + (size_t)cur * 4 + 3, a3);
        a0 = a1 = a2 = a3 = 0; cur = r;
      }
      const half4 f = *(const half4*)(f2h + (size_t)c * 4);
      a0 += v * (float)f[0]; a1 += v * (float)f[1];
      a2 += v * (float)f[2]; a3 += v * (float)f[3];
    }
  }
  atomicAdd(rf + (size_t)cur * 4 + 0, a0);
  atomicAdd(rf + (size_t)cur * 4 + 1, a1);
  atomicAdd(rf + (size_t)cur * 4 + 2, a2);
  atomicAdd(rf + (size_t)cur * 4 + 3, a3);
}

__global__ __launch_bounds__(256)
void write_fbp(const float* __restrict__ rf, float* __restrict__ out)
{
  int id = blockIdx.x * 256 + threadIdx.x;  // 4*262144 exact
  int b = id >> 18, p = id & 262143;
  out[id] = 4.f * rf[(size_t)p * 4 + b];
}

__global__ __launch_bounds__(256)
void write_outputs(const float* __restrict__ accf, const float* __restrict__ rf,
                   const float* __restrict__ b6, float* __restrict__ out)
{
  int id = blockIdx.x * 256 + threadIdx.x;  // 4*262144 exact
  int b = id >> 18, p = id & 262143;
  out[id] = accf[id] * 0.2f + b6[0] + 4.f * rf[(size_t)p * 4 + b];
}

// ---------------------------------------------------------------------------
extern "C" void kernel_launch(void* const* d_in, const int* in_sizes, int n_in,
                              void* d_out, int out_size, void* d_ws, size_t ws_size,
                              hipStream_t stream)
{
  (void)in_sizes; (void)n_in; (void)out_size;
  const float* inputs   = (const float*)d_in[0];
  const float* w_sin1   = (const float*)d_in[1];
  const float* b_sin1   = (const float*)d_in[2];
  const float* w_sin_mid= (const float*)d_in[3];
  const float* sin_gamma= (const float*)d_in[4];
  const float* sin_beta = (const float*)d_in[5];
  const float* sin_mean = (const float*)d_in[6];
  const float* sin_var  = (const float*)d_in[7];
  const float* w_sin6   = (const float*)d_in[8];
  const float* b_sin6   = (const float*)d_in[9];
  const float* w_ct1    = (const float*)d_in[10];
  const float* b_ct1    = (const float*)d_in[11];
  const float* w_ct_mid = (const float*)d_in[12];
  const float* ct_gamma = (const float*)d_in[13];
  const float* ct_beta  = (const float*)d_in[14];
  const float* ct_mean  = (const float*)d_in[15];
  const float* ct_var   = (const float*)d_in[16];
  const float* w_ct6    = (const float*)d_in[17];
  const float* b_ct6    = (const float*)d_in[18];
  const float* w_b      = (const float*)d_in[19];
  const float* at_vals  = (const float*)d_in[20];
  const int*   at_rows  = (const int*)d_in[21];
  const int*   at_cols  = (const int*)d_in[22];
  float* out = (float*)d_out;

  // full 4-batch mode needs ~279 MB; per-batch split needs ~78 MB.
  const bool full = ws_size >= (size_t)282 * 1024 * 1024;
  const int nbat  = full ? 4 : 1;
  const int npass = full ? 1 : 4;

  char* ws = (char*)d_ws;
  size_t off = 0;
  auto alloc = [&](size_t bytes) {
    char* p = ws + off;
    off = (off + bytes + 255) & ~(size_t)255;
    return p;
  };
  char*     zbuf    = alloc(256);
  _Float16* wmid    = (_Float16*)alloc((size_t)9 * 102400 * 2);
  float*    biasmid = (float*)alloc(9 * 64 * 4);
  _Float16* w6s     = (_Float16*)alloc(3200 * 2);
  float*    rf      = (float*)alloc((size_t)262144 * 16);
  char*     shreg   = alloc((size_t)262144 * 16);  // f2h (2.1MB) / acc_fc (4.18MB) union
  _Float16* act_a   = (_Float16*)alloc((size_t)nbat * 262144 * 128);
  _Float16* act_b   = (_Float16*)alloc((size_t)nbat * 262144 * 128);
  _Float16* f2h    = (_Float16*)shreg;
  float*    acc_fc = (float*)shreg;

  hipMemsetAsync(zbuf, 0, 256, stream);
  hipMemsetAsync(rf, 0, (size_t)262144 * 16, stream);
  hipMemsetAsync(acc_fc, 0, (size_t)262144 * 16, stream);

  prep_weights<<<3613, 256, 0, stream>>>(w_sin_mid, sin_gamma, sin_beta, sin_mean, sin_var,
                                         w_ct_mid, ct_gamma, ct_beta, ct_mean, ct_var,
                                         w_sin6, w_ct6, wmid, biasmid, w6s);

  // ---- sinogram CNN (H=725, W=360) ----
  for (int p = 0; p < npass; ++p) {
    const int b0 = p * nbat;
    conv1_kernel<0><<<dim3(23, 46, nbat), 256, 0, stream>>>(inputs, act_a, w_sin1, b_sin1,
                                                            725, 360, b0);
    _Float16* cur = act_a; _Float16* nxt = act_b;
    for (int i = 0; i < 4; ++i) {
      mid_conv<<<dim3(23, 46, nbat), 256, 0, stream>>>(cur, nxt, acc_fc,
                                                       wmid + (size_t)i * 102400, w6s,
                                                       biasmid + i * 64, zbuf, 725, 360, b0);
      _Float16* t = cur; cur = nxt; nxt = t;
    }
    fc_accum<<<dim3(23, 46, nbat), 256, 0, stream>>>(cur, acc_fc, w_sin6, zbuf, 725, 360, b0);
  }
  write_desin<<<4079, 256, 0, stream>>>(acc_fc, inputs, b_sin6, out);

  // ---- FBP ----
  ramp_filter<<<1440, 128, 0, stream>>>(out, w_b, f2h);
  backproj<<<2048, 256, 0, stream>>>(at_vals, at_rows, at_cols, f2h, rf);
  write_fbp<<<4096, 256, 0, stream>>>(rf, out + 2092576);

  // ---- image CNN (H=W=512) ----
  hipMemsetAsync(acc_fc, 0, (size_t)262144 * 16, stream);
  for (int p = 0; p < npass; ++p) {
    const int b0 = p * nbat;
    conv1_kernel<1><<<dim3(32, 32, nbat), 256, 0, stream>>>(rf, act_a, w_ct1, b_ct1,
                                                            512, 512, b0);
    _Float16* cur = act_a; _Float16* nxt = act_b;
    for (int i = 0; i < 5; ++i) {
      mid_conv<<<dim3(32, 32, nbat), 256, 0, stream>>>(cur, nxt, acc_fc,
                                                       wmid + (size_t)(4 + i) * 102400,
                                                       w6s + 1600,
                                                       biasmid + (4 + i) * 64, zbuf,
                                                       512, 512, b0);
      _Float16* t = cur; cur = nxt; nxt = t;
    }
    fc_accum<<<dim3(32, 32, nbat), 256, 0, stream>>>(cur, acc_fc, w_ct6, zbuf, 512, 512, b0);
  }
  write_outputs<<<4096, 256, 0, stream>>>(acc_fc, rf, b_ct6, out + 1044000);
}

// Round 4
// 2751.595 us; speedup vs baseline: 1.4169x; 1.1173x over previous
//
#include <hip/hip_runtime.h>
#include <stdint.h>

#define S_DET 725
#define S_ANG 360
#define OUTD  512
#define NB    4

typedef float    float4v __attribute__((ext_vector_type(4)));
typedef int      int4v   __attribute__((ext_vector_type(4)));
typedef _Float16 half8   __attribute__((ext_vector_type(8)));
typedef _Float16 half4   __attribute__((ext_vector_type(4)));
typedef _Float16 half2v  __attribute__((ext_vector_type(2)));

#define GAS __attribute__((address_space(1)))
#define LAS __attribute__((address_space(3)))

// async global->LDS, 16B per lane, LDS dst wave-uniform (lane i writes dst+16*i)
__device__ __forceinline__ void async16(const void* src, void* lds) {
  __builtin_amdgcn_global_load_lds((const GAS void*)(uintptr_t)src,
                                   (LAS void*)(uint32_t)(uintptr_t)lds, 16, 0, 0);
}

// ---------------------------------------------------------------------------
// Weight prep: fold BN into weights/bias, cast f16, transpose to [tap][n][k]
// with 16B-chunk XOR swizzle (chunk g of row n at slot g^(n&7)). Tail ids
// pack w_sin6/w_ct6 to f16 [tap][k] for the fused-fc MFMA row.
// ---------------------------------------------------------------------------
__global__ __launch_bounds__(256)
void prep_weights(const float* __restrict__ wsin, const float* __restrict__ sg,
                  const float* __restrict__ sb,  const float* __restrict__ sm,
                  const float* __restrict__ sv,
                  const float* __restrict__ wct, const float* __restrict__ cg,
                  const float* __restrict__ cbt, const float* __restrict__ cm,
                  const float* __restrict__ cv,
                  const float* __restrict__ wsin6, const float* __restrict__ wct6,
                  _Float16* __restrict__ wout, float* __restrict__ bout,
                  _Float16* __restrict__ w6out)
{
  int id = blockIdx.x * 256 + threadIdx.x;
  if (id < 9 * 102400) {
    int l   = id / 102400;          // layer 0..8 (0-3 sinogram, 4-8 image)
    int rem = id - l * 102400;      // t*4096 + k*64 + n  (source [5][5][64][64])
    int t = rem >> 12;
    int kn = rem & 4095;
    int k = kn >> 6, n = kn & 63;
    const float *w, *g, *b, *m, *v;
    if (l < 4) { w = wsin + l*102400; g = sg + l*64; b = sb + l*64; m = sm + l*64; v = sv + l*64; }
    else { int li = l - 4; w = wct + li*102400; g = cg + li*64; b = cbt + li*64; m = cm + li*64; v = cv + li*64; }
    float s = g[n] * rsqrtf(v[n] + 1e-3f);
    float val = w[rem] * s;
    int slot = (k >> 3) ^ (n & 7);
    wout[(size_t)l*102400 + t*4096 + n*64 + slot*8 + (k & 7)] = (_Float16)val;
    if (rem < 64)  // t==0,k==0 -> n==rem
      bout[l*64 + rem] = b[rem] - m[rem] * s;
  } else {
    int r = id - 9 * 102400;
    if (r < 3200)  // [0,1600) sino w6, [1600,3200) ct w6; layout [t*64+k]
      w6out[r] = (_Float16)(r < 1600 ? wsin6[r] : wct6[r - 1600]);
  }
}

// ---------------------------------------------------------------------------
// First conv 1->64, bias+relu, fp32 compute, f16 output [bz][y][x][c].
// IMG=0: src inputs [B,725,360]; IMG=1: src rf table, in = 4*rf[p*4+gb].
// ---------------------------------------------------------------------------
template <int IMG>
__global__ __launch_bounds__(256)
void conv1_kernel(const float* __restrict__ src, _Float16* __restrict__ dst,
                  const float* __restrict__ w1, const float* __restrict__ b1,
                  int H, int W, int b0)
{
  __shared__ __align__(16) float in_s[400];
  __shared__ __align__(16) float w_s[1600];
  __shared__ float b_s[64];
  const int tid = threadIdx.x;
  const int bz = blockIdx.z, gb = b0 + bz;
  const int y0 = blockIdx.y * 16, x0 = blockIdx.x * 16;
  for (int i = tid; i < 1600; i += 256) w_s[i] = w1[i];
  if (tid < 64) b_s[tid] = b1[tid];
  for (int i = tid; i < 400; i += 256) {
    int iy = i / 20, ix = i - iy * 20;
    int y = y0 - 2 + iy, x = x0 - 2 + ix;
    float v = 0.f;
    if (y >= 0 && y < H && x >= 0 && x < W) {
      if (IMG) v = 4.f * src[(size_t)(y * W + x) * 4 + gb];
      else     v = src[((size_t)gb * H + y) * W + x];
    }
    in_s[i] = v;
  }
  __syncthreads();
  const int ty = tid >> 4, tx = tid & 15;
  float acc[64];
#pragma unroll
  for (int c = 0; c < 64; ++c) acc[c] = 0.f;
  int dy = 0, dx = 0;
  for (int t = 0; t < 25; ++t) {
    float v = in_s[(ty + dy) * 20 + tx + dx];
    const float4v* wp = (const float4v*)(w_s + t * 64);
#pragma unroll
    for (int c = 0; c < 16; ++c) {
      float4v w4 = wp[c];
      acc[4*c+0] += v * w4[0]; acc[4*c+1] += v * w4[1];
      acc[4*c+2] += v * w4[2]; acc[4*c+3] += v * w4[3];
    }
    if (++dx == 5) { dx = 0; ++dy; }
  }
  const int y = y0 + ty, x = x0 + tx;
  if (y < H && x < W) {
    uint32_t* dp = (uint32_t*)(dst + ((size_t)(bz * H + y) * W + x) * 64);
#pragma unroll
    for (int c = 0; c < 32; ++c) {
      float v0 = acc[2*c]   + b_s[2*c];   v0 = v0 > 0.f ? v0 : 0.f;
      float v1 = acc[2*c+1] + b_s[2*c+1]; v1 = v1 > 0.f ? v1 : 0.f;
      half2v h = { (_Float16)v0, (_Float16)v1 };
      dp[c] = __builtin_bit_cast(uint32_t, h);
    }
  }
}

// ---------------------------------------------------------------------------
// Residual conv 64->64 + folded-BN bias + relu via MFMA 16x16x32 f16, PLUS
// fused fc: w6 rides as an extra A-operand whose m=0 row is w6[tap][k]
// (other rows read a zero slot), consuming the same B pixel frags -> fc of
// the INPUT map lands in acc6 for free; += into accum (block interiors are
// disjoint). Output tile 16x16; input tile 20x20 px x 64ch in LDS.
// ---------------------------------------------------------------------------
__global__ __launch_bounds__(256, 2)
void mid_conv(const _Float16* __restrict__ src, _Float16* __restrict__ dst,
              float* __restrict__ accum,
              const _Float16* __restrict__ wt, const _Float16* __restrict__ w6g,
              const float* __restrict__ bias, const char* __restrict__ zbuf,
              int H, int W, int b0)
{
  __shared__ __align__(16) char smem[51200 + 2 * 8192 + 3200 + 16];
  char* const atile = smem;                       // 400 px * 128B
  char* const wbuf  = smem + 51200;               // 2 x 8KB weight dbuf
  _Float16* const w6l = (_Float16*)(smem + 51200 + 16384);  // 25x64 f16
  char* const zl = smem + 51200 + 16384 + 3200;   // 16B zeros
  const int tid = threadIdx.x;
  const int wv = tid >> 6, ln = tid & 63;
  const int bz = blockIdx.z, gb = b0 + bz;
  const int y0 = blockIdx.y * 16, x0 = blockIdx.x * 16;

  if (tid < 200) ((half8*)w6l)[tid] = ((const half8*)w6g)[tid];
  if (tid < 4) ((int*)zl)[tid] = 0;

  // stage input tile: 400 px * 8 chunks = 50 wave-instructions
  for (int inst = wv; inst < 50; inst += 4) {
    const int slot = inst * 64 + ln;
    const int p = slot >> 3, gp = slot & 7;
    const int g = gp ^ (p & 7);
    const int iy = p / 20, ix = p - iy * 20;
    const int y = y0 - 2 + iy, x = x0 - 2 + ix;
    const char* sp = (y >= 0 && y < H && x >= 0 && x < W)
        ? (const char*)(src + ((size_t)(bz * H + y) * W + x) * 64) + g * 16
        : zbuf + g * 16;
    async16(sp, atile + inst * 1024);
  }
  // tap-0 weights into buffer 0
#pragma unroll
  for (int j = 0; j < 2; ++j) {
    const int inst = wv * 2 + j;
    async16((const char*)wt + inst * 1024 + ln * 16, wbuf + inst * 1024);
  }
  __syncthreads();

  float4v acc[4][4];
  float4v acc6[4];
#pragma unroll
  for (int pi = 0; pi < 4; ++pi) {
    acc6[pi] = (float4v){0.f, 0.f, 0.f, 0.f};
#pragma unroll
    for (int ci = 0; ci < 4; ++ci) acc[pi][ci] = (float4v){0.f, 0.f, 0.f, 0.f};
  }

  int dy = 0, dx = 0;
  for (int t = 0; t < 25; ++t) {
    if (t < 24) {  // prefetch next tap's weights into the other buffer
      char* wdst = wbuf + ((t + 1) & 1) * 8192;
#pragma unroll
      for (int j = 0; j < 2; ++j) {
        const int inst = wv * 2 + j;
        async16((const char*)wt + (t + 1) * 8192 + inst * 1024 + ln * 16,
                wdst + inst * 1024);
      }
    }
    const char* wb = wbuf + (t & 1) * 8192;
#pragma unroll
    for (int kc = 0; kc < 2; ++kc) {
      const int g0 = kc * 4 + (ln >> 4);
      half8 wf[4], af[4], wf6;
#pragma unroll
      for (int ci = 0; ci < 4; ++ci) {
        const int ch = ci * 16 + (ln & 15);
        wf[ci] = *(const half8*)(wb + ch * 128 + ((g0 ^ (ch & 7)) << 4));
      }
      wf6 = *(const half8*)((ln & 15) == 0
                ? (const char*)(w6l + t * 64 + kc * 32 + ((ln >> 4) << 3))
                : zl);
#pragma unroll
      for (int pi = 0; pi < 4; ++pi) {
        const int p = (wv * 4 + pi + dy) * 20 + (ln & 15) + dx;
        af[pi] = *(const half8*)(atile + p * 128 + ((g0 ^ (p & 7)) << 4));
      }
#pragma unroll
      for (int pi = 0; pi < 4; ++pi) {
#pragma unroll
        for (int ci = 0; ci < 4; ++ci)
          acc[pi][ci] = __builtin_amdgcn_mfma_f32_16x16x32_f16(
              wf[ci], af[pi], acc[pi][ci], 0, 0, 0);
        acc6[pi] = __builtin_amdgcn_mfma_f32_16x16x32_f16(
            wf6, af[pi], acc6[pi], 0, 0, 0);
      }
    }
    if (++dx == 5) { dx = 0; ++dy; }
    __syncthreads();
  }

  // epilogue: D[m=ch][n=px]; lane holds 4 consecutive channels of 1 pixel
  const int tx = ln & 15;
  const int x = x0 + tx;
#pragma unroll
  for (int pi = 0; pi < 4; ++pi) {
    const int y = y0 + wv * 4 + pi;
    if (y < H && x < W) {
      _Float16* dp = dst + ((size_t)(bz * H + y) * W + x) * 64;
#pragma unroll
      for (int ci = 0; ci < 4; ++ci) {
        const int cbase = ci * 16 + (ln >> 4) * 4;
        const float4v bv = *(const float4v*)(bias + cbase);
        half4 h;
#pragma unroll
        for (int r = 0; r < 4; ++r) {
          float v = acc[pi][ci][r] + bv[r];
          v = v > 0.f ? v : 0.f;
          h[r] = (_Float16)v;
        }
        *(half4*)(dp + cbase) = h;
      }
    }
  }
  // fused fc of the input map: D row m=0 lives in lanes 0..15, reg 0
  if (ln < 16) {
#pragma unroll
    for (int pi = 0; pi < 4; ++pi) {
      const int y = y0 + wv * 4 + pi, x2 = x0 + ln;
      if (y < H && x2 < W)
        accum[((size_t)gb * H + y) * W + x2] += acc6[pi][0];
    }
  }
}

// ---------------------------------------------------------------------------
// Standalone 64->1 conv (only for the LAST activation map of each chain).
// ---------------------------------------------------------------------------
__global__ __launch_bounds__(256, 2)
void fc_accum(const _Float16* __restrict__ src, float* __restrict__ accum,
              const float* __restrict__ w6, const char* __restrict__ zbuf,
              int H, int W, int b0)
{
  __shared__ __align__(16) char smem[51200 + 3200];
  char* const atile = smem;
  _Float16* const wl = (_Float16*)(smem + 51200);
  const int tid = threadIdx.x;
  const int wv = tid >> 6, ln = tid & 63;
  const int bz = blockIdx.z, gb = b0 + bz;
  const int y0 = blockIdx.y * 16, x0 = blockIdx.x * 16;
  for (int i = tid; i < 1600; i += 256) wl[i] = (_Float16)w6[i];
  for (int inst = wv; inst < 50; inst += 4) {
    const int slot = inst * 64 + ln;
    const int p = slot >> 3, gp = slot & 7;
    const int g = gp ^ (p & 7);
    const int iy = p / 20, ix = p - iy * 20;
    const int y = y0 - 2 + iy, x = x0 - 2 + ix;
    const char* sp = (y >= 0 && y < H && x >= 0 && x < W)
        ? (const char*)(src + ((size_t)(bz * H + y) * W + x) * 64) + g * 16
        : zbuf + g * 16;
    async16(sp, atile + inst * 1024);
  }
  __syncthreads();
  const int ty = tid >> 4, tx = tid & 15;
  float sum = 0.f;
  int dy = 0, dxx = 0;
  for (int t = 0; t < 25; ++t) {
    const int p = (ty + dy) * 20 + tx + dxx;
    const char* pb = atile + p * 128;
    const int pk = p & 7;
    const half2v* wp = (const half2v*)(wl + t * 64);
#pragma unroll
    for (int g = 0; g < 8; ++g) {
      half8 h = *(const half8*)(pb + ((g ^ pk) << 4));
#pragma unroll
      for (int q = 0; q < 4; ++q) {
        half2v a = { h[2*q], h[2*q+1] };
        sum = __builtin_amdgcn_fdot2(a, wp[g * 4 + q], sum, false);
      }
    }
    if (++dxx == 5) { dxx = 0; ++dy; }
  }
  const int y = y0 + ty, x = x0 + tx;
  if (y < H && x < W) accum[((size_t)gb * H + y) * W + x] += sum;
}

// ---------------------------------------------------------------------------
__global__ __launch_bounds__(256)
void write_desin(const float* __restrict__ accf, const float* __restrict__ inputs,
                 const float* __restrict__ b6, float* __restrict__ out)
{
  int id = blockIdx.x * 256 + threadIdx.x;
  if (id < NB * S_DET * S_ANG) out[id] = accf[id] * 0.25f + b6[0] + inputs[id];
}

// ---------------------------------------------------------------------------
// Ramp filter: 725-tap SAME 1D conv along detector axis; one block per
// (batch, angle); output packed f16 rows f2h[(a*725+s)*4 + b].
// ---------------------------------------------------------------------------
__global__ __launch_bounds__(128)
void ramp_filter(const float* __restrict__ desin, const float* __restrict__ wb,
                 _Float16* __restrict__ f2h)
{
  __shared__ float col[1472];   // zero-padded: data at [368, 368+725)
  __shared__ float wl[725];
  const int blk = blockIdx.x;
  const int b = blk / 360, a = blk - b * 360;
  const int tid = threadIdx.x;
  for (int i = tid; i < 1472; i += 128) col[i] = 0.f;
  for (int i = tid; i < 725; i += 128) wl[i] = wb[i];
  __syncthreads();
  for (int i = tid; i < 725; i += 128) col[368 + i] = desin[(b * 725 + i) * 360 + a];
  __syncthreads();
  const int s0 = tid * 6;
  if (s0 < 725) {
    float o0 = 0, o1 = 0, o2 = 0, o3 = 0, o4 = 0, o5 = 0;
    const float* cb = col + 6 + s0;  // cb[t+j] = x[s0+j + t - 362]
    float r0 = cb[0], r1 = cb[1], r2 = cb[2], r3 = cb[3], r4 = cb[4], r5 = cb[5];
    for (int t = 0; t < 725; ++t) {
      float w = wl[t];
      o0 += r0 * w; o1 += r1 * w; o2 += r2 * w;
      o3 += r3 * w; o4 += r4 * w; o5 += r5 * w;
      r0 = r1; r1 = r2; r2 = r3; r3 = r4; r4 = r5; r5 = cb[t + 6];
    }
    float o[6] = { o0, o1, o2, o3, o4, o5 };
#pragma unroll
    for (int j = 0; j < 6; ++j)
      if (s0 + j < 725) f2h[((size_t)a * 725 + s0 + j) * 4 + b] = (_Float16)o[j];
  }
}

// ---------------------------------------------------------------------------
// Sparse backprojection: rows sorted -> run-length accumulate 16 nnz/thread,
// flush with 4 atomicAdds on row change. f2h gathers are 8B (fp16 x4).
// Streams (vals/rows/cols) use NON-TEMPORAL loads so the 100 MB of one-shot
// data doesn't evict the 2.1 MB f2h gather table from L2.
// ---------------------------------------------------------------------------
__global__ __launch_bounds__(256)
void backproj(const float* __restrict__ vals, const int* __restrict__ rows,
              const int* __restrict__ cols, const _Float16* __restrict__ f2h,
              float* __restrict__ rf)
{
  const int tid = blockIdx.x * 256 + threadIdx.x;   // 524288 threads
  const int i0 = tid * 16;
  const int4v* rp = (const int4v*)(rows + i0);
  const int4v* cp = (const int4v*)(cols + i0);
  const float4v* vp = (const float4v*)(vals + i0);
  float a0 = 0, a1 = 0, a2 = 0, a3 = 0;
  int4v r0v = __builtin_nontemporal_load(rp);
  int cur = r0v[0];
#pragma unroll
  for (int q = 0; q < 4; ++q) {
    int4v r4 = (q == 0) ? r0v : __builtin_nontemporal_load(rp + q);
    int4v c4 = __builtin_nontemporal_load(cp + q);
    float4v v4 = __builtin_nontemporal_load(vp + q);
#pragma unroll
    for (int u = 0; u < 4; ++u) {
      int r = r4[u]; int c = c4[u]; float v = v4[u];
      if (r != cur) {
        atomicAdd(rf + (size_t)cur * 4 + 0, a0);
        atomicAdd(rf + (size_t)cur * 4 + 1, a1);
        atomicAdd(rf + (size_t)cur * 4 + 2, a2);
        atomicAdd(rf + (size_t)cur * 4 + 3, a3);
        a0 = a1 = a2 = a3 = 0; cur = r;
      }
      const half4 f = *(const half4*)(f2h + (size_t)c * 4);
      a0 += v * (float)f[0]; a1 += v * (float)f[1];
      a2 += v * (float)f[2]; a3 += v * (float)f[3];
    }
  }
  atomicAdd(rf + (size_t)cur * 4 + 0, a0);
  atomicAdd(rf + (size_t)cur * 4 + 1, a1);
  atomicAdd(rf + (size_t)cur * 4 + 2, a2);
  atomicAdd(rf + (size_t)cur * 4 + 3, a3);
}

__global__ __launch_bounds__(256)
void write_fbp(const float* __restrict__ rf, float* __restrict__ out)
{
  int id = blockIdx.x * 256 + threadIdx.x;  // 4*262144 exact
  int b = id >> 18, p = id & 262143;
  out[id] = 4.f * rf[(size_t)p * 4 + b];
}

__global__ __launch_bounds__(256)
void write_outputs(const float* __restrict__ accf, const float* __restrict__ rf,
                   const float* __restrict__ b6, float* __restrict__ out)
{
  int id = blockIdx.x * 256 + threadIdx.x;  // 4*262144 exact
  int b = id >> 18, p = id & 262143;
  out[id] = accf[id] * 0.2f + b6[0] + 4.f * rf[(size_t)p * 4 + b];
}

// ---------------------------------------------------------------------------
extern "C" void kernel_launch(void* const* d_in, const int* in_sizes, int n_in,
                              void* d_out, int out_size, void* d_ws, size_t ws_size,
                              hipStream_t stream)
{
  (void)in_sizes; (void)n_in; (void)out_size;
  const float* inputs   = (const float*)d_in[0];
  const float* w_sin1   = (const float*)d_in[1];
  const float* b_sin1   = (const float*)d_in[2];
  const float* w_sin_mid= (const float*)d_in[3];
  const float* sin_gamma= (const float*)d_in[4];
  const float* sin_beta = (const float*)d_in[5];
  const float* sin_mean = (const float*)d_in[6];
  const float* sin_var  = (const float*)d_in[7];
  const float* w_sin6   = (const float*)d_in[8];
  const float* b_sin6   = (const float*)d_in[9];
  const float* w_ct1    = (const float*)d_in[10];
  const float* b_ct1    = (const float*)d_in[11];
  const float* w_ct_mid = (const float*)d_in[12];
  const float* ct_gamma = (const float*)d_in[13];
  const float* ct_beta  = (const float*)d_in[14];
  const float* ct_mean  = (const float*)d_in[15];
  const float* ct_var   = (const float*)d_in[16];
  const float* w_ct6    = (const float*)d_in[17];
  const float* b_ct6    = (const float*)d_in[18];
  const float* w_b      = (const float*)d_in[19];
  const float* at_vals  = (const float*)d_in[20];
  const int*   at_rows  = (const int*)d_in[21];
  const int*   at_cols  = (const int*)d_in[22];
  float* out = (float*)d_out;

  // adaptive batching: fixed tables ~11 MB; activations 2 x nbat x 33.55 MB.
  const size_t base = (size_t)11 << 20;
  const size_t act_per_batch = (size_t)2 * 262144 * 128;  // both ping-pong bufs
  int nbat = 1;
  if (ws_size >= base + 4 * act_per_batch) nbat = 4;
  else if (ws_size >= base + 2 * act_per_batch) nbat = 2;
  const int npass = 4 / nbat;

  char* ws = (char*)d_ws;
  size_t off = 0;
  auto alloc = [&](size_t bytes) {
    char* p = ws + off;
    off = (off + bytes + 255) & ~(size_t)255;
    return p;
  };
  char*     zbuf    = alloc(256);
  _Float16* wmid    = (_Float16*)alloc((size_t)9 * 102400 * 2);
  float*    biasmid = (float*)alloc(9 * 64 * 4);
  _Float16* w6s     = (_Float16*)alloc(3200 * 2);
  float*    rf      = (float*)alloc((size_t)262144 * 16);
  char*     shreg   = alloc((size_t)262144 * 16);  // f2h (2.1MB) / acc_fc (4.18MB) union
  _Float16* act_a   = (_Float16*)alloc((size_t)nbat * 262144 * 128);
  _Float16* act_b   = (_Float16*)alloc((size_t)nbat * 262144 * 128);
  _Float16* f2h    = (_Float16*)shreg;
  float*    acc_fc = (float*)shreg;

  hipMemsetAsync(zbuf, 0, 256, stream);
  hipMemsetAsync(rf, 0, (size_t)262144 * 16, stream);
  hipMemsetAsync(acc_fc, 0, (size_t)262144 * 16, stream);

  prep_weights<<<3613, 256, 0, stream>>>(w_sin_mid, sin_gamma, sin_beta, sin_mean, sin_var,
                                         w_ct_mid, ct_gamma, ct_beta, ct_mean, ct_var,
                                         w_sin6, w_ct6, wmid, biasmid, w6s);

  // ---- sinogram CNN (H=725, W=360) ----
  for (int p = 0; p < npass; ++p) {
    const int b0 = p * nbat;
    conv1_kernel<0><<<dim3(23, 46, nbat), 256, 0, stream>>>(inputs, act_a, w_sin1, b_sin1,
                                                            725, 360, b0);
    _Float16* cur = act_a; _Float16* nxt = act_b;
    for (int i = 0; i < 4; ++i) {
      mid_conv<<<dim3(23, 46, nbat), 256, 0, stream>>>(cur, nxt, acc_fc,
                                                       wmid + (size_t)i * 102400, w6s,
                                                       biasmid + i * 64, zbuf, 725, 360, b0);
      _Float16* t = cur; cur = nxt; nxt = t;
    }
    fc_accum<<<dim3(23, 46, nbat), 256, 0, stream>>>(cur, acc_fc, w_sin6, zbuf, 725, 360, b0);
  }
  write_desin<<<4079, 256, 0, stream>>>(acc_fc, inputs, b_sin6, out);

  // ---- FBP ----
  ramp_filter<<<1440, 128, 0, stream>>>(out, w_b, f2h);
  backproj<<<2048, 256, 0, stream>>>(at_vals, at_rows, at_cols, f2h, rf);
  write_fbp<<<4096, 256, 0, stream>>>(rf, out + 2092576);

  // ---- image CNN (H=W=512) ----
  hipMemsetAsync(acc_fc, 0, (size_t)262144 * 16, stream);
  for (int p = 0; p < npass; ++p) {
    const int b0 = p * nbat;
    conv1_kernel<1><<<dim3(32, 32, nbat), 256, 0, stream>>>(rf, act_a, w_ct1, b_ct1,
                                                            512, 512, b0);
    _Float16* cur = act_a; _Float16* nxt = act_b;
    for (int i = 0; i < 5; ++i) {
      mid_conv<<<dim3(32, 32, nbat), 256, 0, stream>>>(cur, nxt, acc_fc,
                                                       wmid + (size_t)(4 + i) * 102400,
                                                       w6s + 1600,
                                                       biasmid + (4 + i) * 64, zbuf,
                                                       512, 512, b0);
      _Float16* t = cur; cur = nxt; nxt = t;
    }
    fc_accum<<<dim3(32, 32, nbat), 256, 0, stream>>>(cur, acc_fc, w_ct6, zbuf, 512, 512, b0);
  }
  write_outputs<<<4096, 256, 0, stream>>>(acc_fc, rf, b_ct6, out + 1044000);
}